// Round 9
// baseline (373.058 us; speedup 1.0000x reference)
//
#include <hip/hip_runtime.h>

#define NN 100000
#define NE 1600000
#define FD 128
#define NG 64
#define OUTD 64

typedef __attribute__((ext_vector_type(8))) short bf16x8;
typedef __attribute__((ext_vector_type(4))) float f32x4;
typedef __attribute__((ext_vector_type(2))) float f32x2;
typedef __attribute__((ext_vector_type(8))) unsigned short u16x8;

static __device__ __forceinline__ void atomAddF(float* p, float v) {
    __hip_atomic_fetch_add(p, v, __ATOMIC_RELAXED, __HIP_MEMORY_SCOPE_AGENT);
}
static __device__ __forceinline__ int atomAddI(int* p, int v) {
    return __hip_atomic_fetch_add(p, v, __ATOMIC_RELAXED, __HIP_MEMORY_SCOPE_AGENT);
}
// fp32 -> bf16 round-to-nearest-even
static __device__ __forceinline__ unsigned short f2bf(float f) {
    unsigned int u = __float_as_uint(f);
    u += 0x7FFFu + ((u >> 16) & 1u);
    return (unsigned short)(u >> 16);
}
static __device__ __forceinline__ float bf2f(unsigned short h) {
    return __uint_as_float(((unsigned int)h) << 16);
}
// fp32 -> fp8 e4m3 (OCP on gfx950), HW convert
static __device__ __forceinline__ unsigned char f2fp8(float v) {
    return (unsigned char)(__builtin_amdgcn_cvt_pk_fp8_f32(v, v, 0, false) & 0xff);
}

// ===== k_prep: [0..6249] degree hist + graph counts; [6250..] Wt + dummy rows =====
__global__ __launch_bounds__(256) void k_prep(
    const int* __restrict__ dst, const int* __restrict__ gid,
    int* __restrict__ degi, float* __restrict__ gcount,
    const float* __restrict__ W1, const float* __restrict__ W2,
    unsigned short* __restrict__ W1t, unsigned short* __restrict__ W2t,
    unsigned short* __restrict__ Ydummy, unsigned int* __restrict__ Y8dummy)
{
    if (blockIdx.x < 6250) {
        __shared__ float c[NG];
        if (threadIdx.x < NG) c[threadIdx.x] = 0.0f;
        __syncthreads();
        int i = blockIdx.x * 256 + threadIdx.x;
        if (i < NE) atomAddI(&degi[dst[i]], 1);
        if (i < NN) atomicAdd(&c[gid[i]], 1.0f);
        __syncthreads();
        if (threadIdx.x < NG) {
            float v = c[threadIdx.x];
            if (v != 0.0f) atomAddF(&gcount[threadIdx.x], v);
        }
    } else {
        int idx = (blockIdx.x - 6250) * 256 + threadIdx.x;
        if (idx < 32768) {
            const float* W = (idx < 16384) ? W1 : W2;
            unsigned short* Wt = (idx < 16384) ? W1t : W2t;
            int i = idx & 16383;
            int k = i >> 7, n = i & 127;
            Wt[n * 128 + k] = f2bf(W[i]);
        } else if (idx < 32768 + FD) {
            Ydummy[idx - 32768] = 0;          // zero bf16 Y row NN
        } else if (idx < 32768 + FD + 32) {
            Y8dummy[idx - 32768 - FD] = 0;    // zero fp8 Y row NN (32 uints)
        }
    }
}

// ===== CSR range claim, buckets padded to multiples of 8 =====
__global__ void k_off(const int* __restrict__ degi, int* __restrict__ cnt,
                      int* __restrict__ off, int* __restrict__ cursor,
                      int* __restrict__ eidx) {
    int i = blockIdx.x * 256 + threadIdx.x;
    int lane = threadIdx.x & 63;
    int d = (i < NN) ? degi[i] : 0;
    int rd = (d + 7) & ~7;
    int incl = rd;
    #pragma unroll
    for (int s = 1; s < 64; s <<= 1) {
        int n = __shfl_up(incl, s, 64);
        if (lane >= s) incl += n;
    }
    int base = 0;
    if (lane == 63) base = atomAddI(cnt, incl);
    base = __shfl(base, 63, 64);
    if (i < NN) {
        int o = base + incl - rd;
        off[i] = o;
        cursor[i] = o;
        for (int j = d; j < rd; ++j) eidx[o + j] = NN;
    }
}

// ===== no-LDS MFMA gemm body: Y (bf16+fp8) = A @ W, A fp32 from global =====
static __device__ __forceinline__ void gemm_body(
    int base, const float* __restrict__ feat, const unsigned short* __restrict__ Wt,
    unsigned short* __restrict__ Y, unsigned char* __restrict__ Y8)
{
    const int lane = threadIdx.x & 63;
    const int w = threadIdx.x >> 6;
    const int r = lane & 15;
    const int kb = lane >> 4;
    const int row = base + w * 16 + r;
    const bool rok = row < NN;

    bf16x8 a[4];
    #pragma unroll
    for (int kt = 0; kt < 4; ++kt) {
        float4 lo = {0,0,0,0}, hi = {0,0,0,0};
        if (rok) {
            const float4* p = reinterpret_cast<const float4*>(
                feat + (size_t)row * FD + kt * 32 + kb * 8);
            lo = p[0]; hi = p[1];
        }
        bf16x8 t;
        t[0] = (short)f2bf(lo.x); t[1] = (short)f2bf(lo.y);
        t[2] = (short)f2bf(lo.z); t[3] = (short)f2bf(lo.w);
        t[4] = (short)f2bf(hi.x); t[5] = (short)f2bf(hi.y);
        t[6] = (short)f2bf(hi.z); t[7] = (short)f2bf(hi.w);
        a[kt] = t;
    }

    f32x4 acc[8];
    #pragma unroll
    for (int ct = 0; ct < 8; ++ct) acc[ct] = (f32x4){0.f, 0.f, 0.f, 0.f};

    const int n = lane & 15;
    #pragma unroll
    for (int ct = 0; ct < 8; ++ct) {
        int col = ct * 16 + n;
        #pragma unroll
        for (int kt = 0; kt < 4; ++kt) {
            bf16x8 b = *reinterpret_cast<const bf16x8*>(
                Wt + (size_t)col * FD + kt * 32 + kb * 8);
            acc[ct] = __builtin_amdgcn_mfma_f32_16x16x32_bf16(a[kt], b, acc[ct], 0, 0, 0);
        }
    }

    const int rbase = base + w * 16 + (lane >> 4) * 4;
    #pragma unroll
    for (int reg = 0; reg < 4; ++reg) {
        int node = rbase + reg;
        if (node < NN) {
            #pragma unroll
            for (int ct = 0; ct < 8; ++ct) {
                float v = acc[ct][reg];
                Y[(size_t)node * FD + ct * 16 + n] = f2bf(v);
                Y8[(size_t)node * FD + ct * 16 + n] = f2fp8(v);
            }
        }
    }
}

// ===== k_work: [g%5==0] gemm1 (no LDS); else CSR fill =====
__global__ __launch_bounds__(256) void k_work(
    const int* __restrict__ src, const int* __restrict__ dst,
    int* __restrict__ cursor, int* __restrict__ eidx,
    const float* __restrict__ feat, const unsigned short* __restrict__ Wt,
    unsigned short* __restrict__ Y, unsigned char* __restrict__ Y8)
{
    int g = blockIdx.x;
    if (g % 5 == 0) {
        gemm_body((g / 5) * 64, feat, Wt, Y, Y8);
    } else {
        int fb = g - g / 5 - 1;
        int e = fb * 256 + threadIdx.x;
        if (e < NE) {
            int v = dst[e];
            int p = atomAddI(&cursor[v], 1);
            eidx[p] = src[e];
        }
    }
}

// ===== LDS MFMA GEMM for layer 2 (A bf16): Y (bf16+fp8) = A @ W =====
__global__ __launch_bounds__(256) void k_gemm2(
    const unsigned short* __restrict__ Ain, const unsigned short* __restrict__ Wt,
    unsigned short* __restrict__ Y, unsigned char* __restrict__ Y8)
{
    __shared__ unsigned short As[64 * 128];    // 16 KB
    __shared__ unsigned short Bs[128 * 128];   // 32 KB
    const int tid = threadIdx.x;
    const int base = blockIdx.x * 64;
    char* AsB = reinterpret_cast<char*>(As);
    char* BsB = reinterpret_cast<char*>(Bs);

    {
        const u16x8* Wv = reinterpret_cast<const u16x8*>(Wt);
        #pragma unroll
        for (int i = 0; i < 8; ++i) {
            int idx = i * 256 + tid;
            int n = idx >> 4, s = idx & 15;
            int soff = (s * 16) ^ ((n & 7) << 4);
            *reinterpret_cast<u16x8*>(BsB + n * 256 + soff) = Wv[idx];
        }
    }
    {
        const u16x8* Av = reinterpret_cast<const u16x8*>(Ain);
        #pragma unroll
        for (int i = 0; i < 4; ++i) {
            int idx = i * 256 + tid;
            int r = idx >> 4, s = idx & 15;
            int row = base + r;
            u16x8 v;
            if (row < NN) v = Av[(size_t)row * 16 + s];
            else v = (u16x8){0,0,0,0,0,0,0,0};
            int soff = (s * 16) ^ ((r & 7) << 4);
            *reinterpret_cast<u16x8*>(AsB + r * 256 + soff) = v;
        }
    }
    __syncthreads();

    const int lane = tid & 63;
    const int w = tid >> 6;
    const int r = w * 16 + (lane & 15);
    const int kb = lane >> 4;
    const int n = lane & 15;

    bf16x8 a[4];
    #pragma unroll
    for (int kt = 0; kt < 4; ++kt) {
        int boff = (kt * 64 + kb * 16) ^ ((r & 7) << 4);
        a[kt] = *reinterpret_cast<bf16x8*>(AsB + r * 256 + boff);
    }

    f32x4 acc[8];
    #pragma unroll
    for (int ct = 0; ct < 8; ++ct) acc[ct] = (f32x4){0.f, 0.f, 0.f, 0.f};

    #pragma unroll
    for (int ct = 0; ct < 8; ++ct) {
        int col = ct * 16 + n;
        #pragma unroll
        for (int kt = 0; kt < 4; ++kt) {
            int boff = (kt * 64 + kb * 16) ^ ((col & 7) << 4);
            bf16x8 b = *reinterpret_cast<bf16x8*>(BsB + col * 256 + boff);
            acc[ct] = __builtin_amdgcn_mfma_f32_16x16x32_bf16(a[kt], b, acc[ct], 0, 0, 0);
        }
    }

    const int rbase = base + w * 16 + (lane >> 4) * 4;
    #pragma unroll
    for (int reg = 0; reg < 4; ++reg) {
        int node = rbase + reg;
        if (node < NN) {
            #pragma unroll
            for (int ct = 0; ct < 8; ++ct) {
                float v = acc[ct][reg];
                Y[(size_t)node * FD + ct * 16 + n] = f2bf(v);
                Y8[(size_t)node * FD + ct * 16 + n] = f2fp8(v);
            }
        }
    }
}

// ===== gather: H[v] = relu(Y[v] + mean_{u->v} Y8[u] + bias) =====
// 8 threads/node x 16 feats; each edge row (128B fp8) = 8 lanes x 16B uint4
// -> 8 load instructions per edge (issue-bound lever). 8-chunk shfl broadcast.
template <bool POOL>
__global__ __launch_bounds__(256) void k_agg(
    const unsigned short* __restrict__ Y, const unsigned char* __restrict__ Y8,
    const int* __restrict__ off, const int* __restrict__ degi,
    const int* __restrict__ eidx, const float* __restrict__ bias,
    unsigned short* __restrict__ H,
    const int* __restrict__ gid, float* __restrict__ hg_sum)
{
    __shared__ float hl[FD];
    int gid0 = 0;
    if (POOL) {
        if (threadIdx.x < FD) hl[threadIdx.x] = 0.0f;
        gid0 = gid[blockIdx.x * 32];
        __syncthreads();
    }
    const int t = blockIdx.x * 256 + threadIdx.x;
    const int v = t >> 3;                 // node
    const int l = t & 7;                  // 16-feature slice
    const int gb = threadIdx.x & 56;      // 8-lane group base within wave
    const int e0 = off[v];
    const int d  = degi[v];
    const int pd = (d + 7) & ~7;

    float a[16];
    #pragma unroll
    for (int j = 0; j < 16; ++j) a[j] = 0.0f;

    const uint4* Y8v = reinterpret_cast<const uint4*>(Y8);
    const int eend = e0 + pd;
    for (int e = e0; e < eend; e += 8) {
        int myidx = eidx[e + l];
        #pragma unroll
        for (int j = 0; j < 8; ++j) {
            int s = __shfl(myidx, gb + j, 64);
            uint4 q = Y8v[(size_t)s * 8 + l];
            f32x2 v0 = __builtin_amdgcn_cvt_pk_f32_fp8((int)q.x, false);
            f32x2 v1 = __builtin_amdgcn_cvt_pk_f32_fp8((int)q.x, true);
            f32x2 v2 = __builtin_amdgcn_cvt_pk_f32_fp8((int)q.y, false);
            f32x2 v3 = __builtin_amdgcn_cvt_pk_f32_fp8((int)q.y, true);
            f32x2 v4 = __builtin_amdgcn_cvt_pk_f32_fp8((int)q.z, false);
            f32x2 v5 = __builtin_amdgcn_cvt_pk_f32_fp8((int)q.z, true);
            f32x2 v6 = __builtin_amdgcn_cvt_pk_f32_fp8((int)q.w, false);
            f32x2 v7 = __builtin_amdgcn_cvt_pk_f32_fp8((int)q.w, true);
            a[0]  += v0[0]; a[1]  += v0[1]; a[2]  += v1[0]; a[3]  += v1[1];
            a[4]  += v2[0]; a[5]  += v2[1]; a[6]  += v3[0]; a[7]  += v3[1];
            a[8]  += v4[0]; a[9]  += v4[1]; a[10] += v5[0]; a[11] += v5[1];
            a[12] += v6[0]; a[13] += v6[1]; a[14] += v7[0]; a[15] += v7[1];
        }
    }

    const float inv = 1.0f / fmaxf((float)d, 1.0f);
    const u16x8* Yv = reinterpret_cast<const u16x8*>(Y);
    u16x8 sv0 = Yv[(size_t)v * 16 + l * 2];
    u16x8 sv1 = Yv[(size_t)v * 16 + l * 2 + 1];
    const float4* bp = reinterpret_cast<const float4*>(bias + l * 16);
    float4 bq0 = bp[0], bq1 = bp[1], bq2 = bp[2], bq3 = bp[3];
    float bb[16] = { bq0.x, bq0.y, bq0.z, bq0.w, bq1.x, bq1.y, bq1.z, bq1.w,
                     bq2.x, bq2.y, bq2.z, bq2.w, bq3.x, bq3.y, bq3.z, bq3.w };

    float hv[16];
    #pragma unroll
    for (int j = 0; j < 8; ++j) {
        hv[j]     = fmaxf(bf2f(sv0[j]) + a[j] * inv + bb[j], 0.0f);
        hv[8 + j] = fmaxf(bf2f(sv1[j]) + a[8 + j] * inv + bb[8 + j], 0.0f);
    }

    if (!POOL) {
        u16x8 o0, o1;
        #pragma unroll
        for (int j = 0; j < 8; ++j) { o0[j] = f2bf(hv[j]); o1[j] = f2bf(hv[8 + j]); }
        u16x8* Hv = reinterpret_cast<u16x8*>(H);
        Hv[(size_t)v * 16 + l * 2]     = o0;
        Hv[(size_t)v * 16 + l * 2 + 1] = o1;
    } else {
        int g = gid[v];
        int fo = l * 16;
        if (g == gid0) {
            #pragma unroll
            for (int j = 0; j < 16; ++j) atomicAdd(&hl[fo + j], hv[j]);
        } else {
            #pragma unroll
            for (int j = 0; j < 16; ++j) atomAddF(&hg_sum[(size_t)g * FD + fo + j], hv[j]);
        }
        __syncthreads();
        if (threadIdx.x < FD)
            atomAddF(&hg_sum[(size_t)gid0 * FD + threadIdx.x], hl[threadIdx.x]);
    }
}

// ===== fused decoder: one block per graph =====
__global__ __launch_bounds__(128) void k_dec(
    const float* __restrict__ hg_sum, const float* __restrict__ gcount,
    const float* __restrict__ Wd1, const float* __restrict__ bd1,
    const float* __restrict__ Wd2, const float* __restrict__ bd2,
    float* __restrict__ out)
{
    __shared__ float hgL[FD];
    __shared__ float t1L[FD];
    const int g = blockIdx.x;
    const int t = threadIdx.x;
    const float invc = 1.0f / fmaxf(gcount[g], 1.0f);

    float v = hg_sum[(size_t)g * FD + t] * invc;
    hgL[t] = v;
    out[(size_t)g * FD + t] = v;
    __syncthreads();

    float acc = bd1[t];
    #pragma unroll 8
    for (int k = 0; k < FD; ++k)
        acc += hgL[k] * Wd1[k * FD + t];
    t1L[t] = fmaxf(acc, 0.0f);
    __syncthreads();

    if (t < OUTD) {
        float acc2 = bd2[t];
        #pragma unroll 8
        for (int k = 0; k < FD; ++k)
            acc2 += t1L[k] * Wd2[k * OUTD + t];
        out[NG * FD + (size_t)g * OUTD + t] = acc2;
    }
}

extern "C" void kernel_launch(void* const* d_in, const int* in_sizes, int n_in,
                              void* d_out, int out_size, void* d_ws, size_t ws_size,
                              hipStream_t stream) {
    const float* feat = (const float*)d_in[0];
    const int*   src  = (const int*)d_in[1];
    const int*   dst  = (const int*)d_in[2];
    const int*   gid  = (const int*)d_in[3];
    const float* W1   = (const float*)d_in[4];
    const float* b1   = (const float*)d_in[5];
    const float* W2   = (const float*)d_in[6];
    const float* b2   = (const float*)d_in[7];
    const float* Wd1  = (const float*)d_in[8];
    const float* bd1  = (const float*)d_in[9];
    const float* Wd2  = (const float*)d_in[10];
    const float* bd2  = (const float*)d_in[11];
    float* out = (float*)d_out;

    // workspace layout (4-byte-word offsets; 8/16B-aligned where vector-accessed)
    char* wsb = (char*)d_ws;
    int*   degi   = (int*)wsb;                              // [100000]
    float* gcount = (float*)(wsb + 100000ll * 4);           // [64]
    float* hg_sum = (float*)(wsb + 100064ll * 4);           // [8192]
    int*   cnt    = (int*)(wsb + 108256ll * 4);             // [1] (pad to 108260)
    int*   off    = (int*)(wsb + 108260ll * 4);             // [100000]
    int*   cursor = (int*)(wsb + 208260ll * 4);             // [100000]
    int*   eidx   = (int*)(wsb + 308260ll * 4);             // [2400000] padded CSR (pad<=8/node)
    unsigned short* W1t = (unsigned short*)(wsb + 2708260ll * 4);  // bf16 [16384]
    unsigned short* W2t = (unsigned short*)(wsb + 2716452ll * 4);  // bf16 [16384]
    unsigned short* Yb  = (unsigned short*)(wsb + 2724644ll * 4);  // bf16 [(NN+1)*128]
    unsigned short* H1  = (unsigned short*)(wsb + 9131108ll * 4);  // bf16 [NN*128]
    unsigned char*  Y8  = (unsigned char*)(wsb + 15531108ll * 4);  // fp8 [(NN+1)*128]

    // zero degi + gcount + hg_sum + cnt
    hipMemsetAsync(d_ws, 0, (size_t)108260 * 4, stream);

    // prep: degree hist + graph counts || Wt convert + dummy-row zeroes
    k_prep<<<6250 + 130, 256, 0, stream>>>(dst, gid, degi, gcount, W1, W2, W1t, W2t,
                                           Yb + (size_t)NN * FD,
                                           (unsigned int*)(Y8 + (size_t)NN * FD));
    // CSR offsets (padded buckets, multiple of 8)
    k_off<<<(NN + 255) / 256, 256, 0, stream>>>(degi, cnt, off, cursor, eidx);
    // fill || gemm1 (y1 = feat @ W1), interleaved 4:1
    k_work<<<7815, 256, 0, stream>>>(src, dst, cursor, eidx, feat, W1t, Yb, Y8);
    // h1 = relu(y1_self + mean-agg(y1_fp8) + b1)
    k_agg<false><<<NN * 8 / 256, 256, 0, stream>>>(Yb, Y8, off, degi, eidx, b1, H1, nullptr, nullptr);
    // y2 = h1 @ W2
    k_gemm2<<<(NN + 63) / 64, 256, 0, stream>>>(H1, W2t, Yb, Y8);
    // h2 pooled per graph
    k_agg<true><<<NN * 8 / 256, 256, 0, stream>>>(Yb, Y8, off, degi, eidx, b2, nullptr, gid, hg_sum);
    // pool divide + decoder
    k_dec<<<NG, 128, 0, stream>>>(hg_sum, gcount, Wd1, bd1, Wd2, bd2, out);
}

// Round 12
// 369.547 us; speedup vs baseline: 1.0095x; 1.0095x over previous
//
#include <hip/hip_runtime.h>

#define NN 100000
#define NE 1600000
#define FD 128
#define NG 64
#define OUTD 64
#define NBIN 391   // ceil(NN/256); block==bin in the scan/fill kernels

typedef __attribute__((ext_vector_type(8))) short bf16x8;
typedef __attribute__((ext_vector_type(4))) float f32x4;
typedef __attribute__((ext_vector_type(2))) float f32x2;
typedef __attribute__((ext_vector_type(8))) unsigned short u16x8;

static __device__ __forceinline__ void atomAddF(float* p, float v) {
    __hip_atomic_fetch_add(p, v, __ATOMIC_RELAXED, __HIP_MEMORY_SCOPE_AGENT);
}
static __device__ __forceinline__ int atomAddI(int* p, int v) {
    return __hip_atomic_fetch_add(p, v, __ATOMIC_RELAXED, __HIP_MEMORY_SCOPE_AGENT);
}
// fp32 -> bf16 round-to-nearest-even
static __device__ __forceinline__ unsigned short f2bf(float f) {
    unsigned int u = __float_as_uint(f);
    u += 0x7FFFu + ((u >> 16) & 1u);
    return (unsigned short)(u >> 16);
}
static __device__ __forceinline__ float bf2f(unsigned short h) {
    return __uint_as_float(((unsigned int)h) << 16);
}
// fp32 -> fp8 e4m3 (OCP on gfx950), HW convert
static __device__ __forceinline__ unsigned char f2fp8(float v) {
    return (unsigned char)(__builtin_amdgcn_cvt_pk_fp8_f32(v, v, 0, false) & 0xff);
}

// ===== k_prep: [0..6249] degree hist + graph counts; [6250..] Wt + dummy rows =====
__global__ __launch_bounds__(256) void k_prep(
    const int* __restrict__ dst, const int* __restrict__ gid,
    int* __restrict__ degi, float* __restrict__ gcount,
    const float* __restrict__ W1, const float* __restrict__ W2,
    unsigned short* __restrict__ W1t, unsigned short* __restrict__ W2t,
    unsigned short* __restrict__ Ydummy, unsigned int* __restrict__ Y8dummy)
{
    if (blockIdx.x < 6250) {
        __shared__ float c[NG];
        if (threadIdx.x < NG) c[threadIdx.x] = 0.0f;
        __syncthreads();
        int i = blockIdx.x * 256 + threadIdx.x;
        if (i < NE) atomAddI(&degi[dst[i]], 1);
        if (i < NN) atomicAdd(&c[gid[i]], 1.0f);
        __syncthreads();
        if (threadIdx.x < NG) {
            float v = c[threadIdx.x];
            if (v != 0.0f) atomAddF(&gcount[threadIdx.x], v);
        }
    } else {
        int idx = (blockIdx.x - 6250) * 256 + threadIdx.x;
        if (idx < 32768) {
            const float* W = (idx < 16384) ? W1 : W2;
            unsigned short* Wt = (idx < 16384) ? W1t : W2t;
            int i = idx & 16383;
            int k = i >> 7, n = i & 127;
            Wt[n * 128 + k] = f2bf(W[i]);
        } else if (idx < 32768 + FD) {
            Ydummy[idx - 32768] = 0;          // zero bf16 Y row NN
        } else if (idx < 32768 + FD + 32) {
            Y8dummy[idx - 32768 - FD] = 0;    // zero fp8 Y row NN (32 uints)
        }
    }
}

// ===== deterministic scan over padded degrees (off[] MONOTONE in node id) =====
__global__ void k_scan1(const int* __restrict__ degi, int* __restrict__ bsum) {
    __shared__ int s[256];
    int i = blockIdx.x * 256 + threadIdx.x;
    int d = (i < NN) ? degi[i] : 0;
    s[threadIdx.x] = (d + 15) & ~15;
    __syncthreads();
    for (int w = 128; w > 0; w >>= 1) {
        if (threadIdx.x < w) s[threadIdx.x] += s[threadIdx.x + w];
        __syncthreads();
    }
    if (threadIdx.x == 0) bsum[blockIdx.x] = s[0];
}

__global__ void k_scan2(const int* __restrict__ bsum, int* __restrict__ boff) {
    __shared__ int s[512];
    int t = threadIdx.x;
    int v = (t < NBIN) ? bsum[t] : 0;
    s[t] = v;
    __syncthreads();
    for (int d = 1; d < 512; d <<= 1) {
        int x = (t >= d) ? s[t - d] : 0;
        __syncthreads();
        s[t] += x;
        __syncthreads();
    }
    if (t < NBIN) boff[t] = s[t] - v;
}

// off[i] = global exclusive prefix of rd; pads bucket tails; inits bin cursor.
__global__ void k_scan3(const int* __restrict__ degi, const int* __restrict__ boff,
                        int* __restrict__ off, int* __restrict__ bcur,
                        int* __restrict__ eidx) {
    __shared__ int s[256];
    int t = threadIdx.x;
    int i = blockIdx.x * 256 + t;
    int d = (i < NN) ? degi[i] : 0;
    int rd = (d + 15) & ~15;
    s[t] = rd;
    __syncthreads();
    for (int dd = 1; dd < 256; dd <<= 1) {
        int x = (t >= dd) ? s[t - dd] : 0;
        __syncthreads();
        s[t] += x;
        __syncthreads();
    }
    if (i < NN) {
        int o = boff[blockIdx.x] + s[t] - rd;
        off[i] = o;
        for (int j = d; j < rd; ++j) eidx[o + j] = NN;   // pad with dummy idx
    }
    if (t == 0) bcur[blockIdx.x * 16] = boff[blockIdx.x]; // bin append cursor
}

// ===== pass 1: bin edges by dst>>8 into pbuf, packed (dstLocal<<17 | src) =====
// Bin regions are contiguous (off monotone) -> appends provably in-bounds.
__global__ void k_bin(const int* __restrict__ src, const int* __restrict__ dst,
                      int* __restrict__ bcur, unsigned int* __restrict__ pbuf) {
    int e = blockIdx.x * 256 + threadIdx.x;
    if (e < NE) {
        int d = dst[e];
        int b = d >> 8;
        int p = atomAddI(&bcur[b * 16], 1);
        pbuf[p] = ((unsigned int)(d & 255) << 17) | (unsigned int)src[e];
    }
}

// ===== no-LDS MFMA gemm body: Y (bf16+fp8) = A @ W, A fp32 from global =====
static __device__ __forceinline__ void gemm_body(
    int base, const float* __restrict__ feat, const unsigned short* __restrict__ Wt,
    unsigned short* __restrict__ Y, unsigned char* __restrict__ Y8)
{
    const int lane = threadIdx.x & 63;
    const int w = threadIdx.x >> 6;
    const int r = lane & 15;
    const int kb = lane >> 4;
    const int row = base + w * 16 + r;
    const bool rok = row < NN;

    bf16x8 a[4];
    #pragma unroll
    for (int kt = 0; kt < 4; ++kt) {
        float4 lo = {0,0,0,0}, hi = {0,0,0,0};
        if (rok) {
            const float4* p = reinterpret_cast<const float4*>(
                feat + (size_t)row * FD + kt * 32 + kb * 8);
            lo = p[0]; hi = p[1];
        }
        bf16x8 t;
        t[0] = (short)f2bf(lo.x); t[1] = (short)f2bf(lo.y);
        t[2] = (short)f2bf(lo.z); t[3] = (short)f2bf(lo.w);
        t[4] = (short)f2bf(hi.x); t[5] = (short)f2bf(hi.y);
        t[6] = (short)f2bf(hi.z); t[7] = (short)f2bf(hi.w);
        a[kt] = t;
    }

    f32x4 acc[8];
    #pragma unroll
    for (int ct = 0; ct < 8; ++ct) acc[ct] = (f32x4){0.f, 0.f, 0.f, 0.f};

    const int n = lane & 15;
    #pragma unroll
    for (int ct = 0; ct < 8; ++ct) {
        int col = ct * 16 + n;
        #pragma unroll
        for (int kt = 0; kt < 4; ++kt) {
            bf16x8 b = *reinterpret_cast<const bf16x8*>(
                Wt + (size_t)col * FD + kt * 32 + kb * 8);
            acc[ct] = __builtin_amdgcn_mfma_f32_16x16x32_bf16(a[kt], b, acc[ct], 0, 0, 0);
        }
    }

    const int rbase = base + w * 16 + (lane >> 4) * 4;
    #pragma unroll
    for (int reg = 0; reg < 4; ++reg) {
        int node = rbase + reg;
        if (node < NN) {
            #pragma unroll
            for (int ct = 0; ct < 8; ++ct) {
                float v = acc[ct][reg];
                Y[(size_t)node * FD + ct * 16 + n] = f2bf(v);
                Y8[(size_t)node * FD + ct * 16 + n] = f2fp8(v);
            }
        }
    }
}

// ===== k_work: [g%5==0] pass-2 fill (bin-local scatter); else gemm1 =====
// fill2 writes stay inside the bin's contiguous eidx range (L2-hot).
__global__ __launch_bounds__(256) void k_work(
    const unsigned int* __restrict__ pbuf, const int* __restrict__ bcur,
    const int* __restrict__ off, int* __restrict__ eidx,
    const float* __restrict__ feat, const unsigned short* __restrict__ Wt,
    unsigned short* __restrict__ Y, unsigned char* __restrict__ Y8)
{
    int g = blockIdx.x;
    if (g % 5 != 0) {
        gemm_body((g - g / 5 - 1) * 64, feat, Wt, Y, Y8);
    } else {
        int b = g / 5;
        __shared__ int cur[256];
        const int t = threadIdx.x;
        const int v = (b << 8) + t;
        cur[t] = (v < NN) ? off[v] : 0;
        __syncthreads();
        const int st = off[b << 8];
        const int en = bcur[b * 16];   // = st + edges_in_bin after k_bin
        for (int i = st + t; i < en; i += 256) {
            unsigned int pk = pbuf[i];
            int dl = (int)(pk >> 17);
            int s  = (int)(pk & 0x1FFFF);
            int p = atomicAdd(&cur[dl], 1);
            eidx[p] = s;
        }
    }
}

// ===== LDS MFMA GEMM for layer 2 (A bf16): Y (bf16+fp8) = A @ W =====
__global__ __launch_bounds__(256) void k_gemm2(
    const unsigned short* __restrict__ Ain, const unsigned short* __restrict__ Wt,
    unsigned short* __restrict__ Y, unsigned char* __restrict__ Y8)
{
    __shared__ unsigned short As[64 * 128];    // 16 KB
    __shared__ unsigned short Bs[128 * 128];   // 32 KB
    const int tid = threadIdx.x;
    const int base = blockIdx.x * 64;
    char* AsB = reinterpret_cast<char*>(As);
    char* BsB = reinterpret_cast<char*>(Bs);

    {
        const u16x8* Wv = reinterpret_cast<const u16x8*>(Wt);
        #pragma unroll
        for (int i = 0; i < 8; ++i) {
            int idx = i * 256 + tid;
            int n = idx >> 4, s = idx & 15;
            int soff = (s * 16) ^ ((n & 7) << 4);
            *reinterpret_cast<u16x8*>(BsB + n * 256 + soff) = Wv[idx];
        }
    }
    {
        const u16x8* Av = reinterpret_cast<const u16x8*>(Ain);
        #pragma unroll
        for (int i = 0; i < 4; ++i) {
            int idx = i * 256 + tid;
            int r = idx >> 4, s = idx & 15;
            int row = base + r;
            u16x8 v;
            if (row < NN) v = Av[(size_t)row * 16 + s];
            else v = (u16x8){0,0,0,0,0,0,0,0};
            int soff = (s * 16) ^ ((r & 7) << 4);
            *reinterpret_cast<u16x8*>(AsB + r * 256 + soff) = v;
        }
    }
    __syncthreads();

    const int lane = tid & 63;
    const int w = tid >> 6;
    const int r = w * 16 + (lane & 15);
    const int kb = lane >> 4;
    const int n = lane & 15;

    bf16x8 a[4];
    #pragma unroll
    for (int kt = 0; kt < 4; ++kt) {
        int boff = (kt * 64 + kb * 16) ^ ((r & 7) << 4);
        a[kt] = *reinterpret_cast<bf16x8*>(AsB + r * 256 + boff);
    }

    f32x4 acc[8];
    #pragma unroll
    for (int ct = 0; ct < 8; ++ct) acc[ct] = (f32x4){0.f, 0.f, 0.f, 0.f};

    #pragma unroll
    for (int ct = 0; ct < 8; ++ct) {
        int col = ct * 16 + n;
        #pragma unroll
        for (int kt = 0; kt < 4; ++kt) {
            int boff = (kt * 64 + kb * 16) ^ ((col & 7) << 4);
            bf16x8 b = *reinterpret_cast<bf16x8*>(BsB + col * 256 + boff);
            acc[ct] = __builtin_amdgcn_mfma_f32_16x16x32_bf16(a[kt], b, acc[ct], 0, 0, 0);
        }
    }

    const int rbase = base + w * 16 + (lane >> 4) * 4;
    #pragma unroll
    for (int reg = 0; reg < 4; ++reg) {
        int node = rbase + reg;
        if (node < NN) {
            #pragma unroll
            for (int ct = 0; ct < 8; ++ct) {
                float v = acc[ct][reg];
                Y[(size_t)node * FD + ct * 16 + n] = f2bf(v);
                Y8[(size_t)node * FD + ct * 16 + n] = f2fp8(v);
            }
        }
    }
}

// ===== gather (round-8 proven shape): H[v] = relu(Y[v] + mean Y8[u] + bias) =====
// 16 thr/node, uint2 loads, 16-chunk shfl broadcast. POOL: per-graph LDS sums.
template <bool POOL>
__global__ __launch_bounds__(256) void k_agg(
    const unsigned short* __restrict__ Y, const unsigned char* __restrict__ Y8,
    const int* __restrict__ off, const int* __restrict__ degi,
    const int* __restrict__ eidx, const float* __restrict__ bias,
    unsigned short* __restrict__ H,
    const int* __restrict__ gid, float* __restrict__ hg_sum)
{
    __shared__ float hl[FD];
    int gid0 = 0;
    if (POOL) {
        if (threadIdx.x < FD) hl[threadIdx.x] = 0.0f;
        gid0 = gid[blockIdx.x * 16];
        __syncthreads();
    }
    const int t = blockIdx.x * 256 + threadIdx.x;
    const int v = t >> 4;                 // node
    const int l = t & 15;                 // 8-feature slice
    const int gb = threadIdx.x & 48;      // 16-lane group base within wave
    const int e0 = off[v];
    const int d  = degi[v];
    const int pd = (d + 15) & ~15;

    float a[8];
    #pragma unroll
    for (int j = 0; j < 8; ++j) a[j] = 0.0f;

    const uint2* Y8v = reinterpret_cast<const uint2*>(Y8);
    const int eend = e0 + pd;
    for (int e = e0; e < eend; e += 16) {
        int myidx = eidx[e + l];
        #pragma unroll
        for (int j = 0; j < 16; ++j) {
            int s = __shfl(myidx, gb + j, 64);
            uint2 q = Y8v[(size_t)s * 16 + l];
            f32x2 v0 = __builtin_amdgcn_cvt_pk_f32_fp8((int)q.x, false);
            f32x2 v1 = __builtin_amdgcn_cvt_pk_f32_fp8((int)q.x, true);
            f32x2 v2 = __builtin_amdgcn_cvt_pk_f32_fp8((int)q.y, false);
            f32x2 v3 = __builtin_amdgcn_cvt_pk_f32_fp8((int)q.y, true);
            a[0] += v0[0]; a[1] += v0[1]; a[2] += v1[0]; a[3] += v1[1];
            a[4] += v2[0]; a[5] += v2[1]; a[6] += v3[0]; a[7] += v3[1];
        }
    }

    const float inv = 1.0f / fmaxf((float)d, 1.0f);
    const u16x8* Yv = reinterpret_cast<const u16x8*>(Y);
    u16x8 sv = Yv[(size_t)v * 16 + l];
    const float4* bp = reinterpret_cast<const float4*>(bias + l * 8);
    float4 b0 = bp[0], b1 = bp[1];
    const float* bb[8] = { &b0.x, &b0.y, &b0.z, &b0.w, &b1.x, &b1.y, &b1.z, &b1.w };

    float hv[8];
    #pragma unroll
    for (int j = 0; j < 8; ++j)
        hv[j] = fmaxf(bf2f(sv[j]) + a[j] * inv + *bb[j], 0.0f);

    if (!POOL) {
        u16x8 o;
        #pragma unroll
        for (int j = 0; j < 8; ++j) o[j] = f2bf(hv[j]);
        reinterpret_cast<u16x8*>(H)[(size_t)v * 16 + l] = o;
    } else {
        int g = gid[v];
        int fo = l * 8;
        if (g == gid0) {
            #pragma unroll
            for (int j = 0; j < 8; ++j) atomicAdd(&hl[fo + j], hv[j]);
        } else {
            #pragma unroll
            for (int j = 0; j < 8; ++j) atomAddF(&hg_sum[(size_t)g * FD + fo + j], hv[j]);
        }
        __syncthreads();
        if (threadIdx.x < FD)
            atomAddF(&hg_sum[(size_t)gid0 * FD + threadIdx.x], hl[threadIdx.x]);
    }
}

// ===== fused decoder: one block per graph =====
__global__ __launch_bounds__(128) void k_dec(
    const float* __restrict__ hg_sum, const float* __restrict__ gcount,
    const float* __restrict__ Wd1, const float* __restrict__ bd1,
    const float* __restrict__ Wd2, const float* __restrict__ bd2,
    float* __restrict__ out)
{
    __shared__ float hgL[FD];
    __shared__ float t1L[FD];
    const int g = blockIdx.x;
    const int t = threadIdx.x;
    const float invc = 1.0f / fmaxf(gcount[g], 1.0f);

    float v = hg_sum[(size_t)g * FD + t] * invc;
    hgL[t] = v;
    out[(size_t)g * FD + t] = v;
    __syncthreads();

    float acc = bd1[t];
    #pragma unroll 8
    for (int k = 0; k < FD; ++k)
        acc += hgL[k] * Wd1[k * FD + t];
    t1L[t] = fmaxf(acc, 0.0f);
    __syncthreads();

    if (t < OUTD) {
        float acc2 = bd2[t];
        #pragma unroll 8
        for (int k = 0; k < FD; ++k)
            acc2 += t1L[k] * Wd2[k * OUTD + t];
        out[NG * FD + (size_t)g * OUTD + t] = acc2;
    }
}

extern "C" void kernel_launch(void* const* d_in, const int* in_sizes, int n_in,
                              void* d_out, int out_size, void* d_ws, size_t ws_size,
                              hipStream_t stream) {
    const float* feat = (const float*)d_in[0];
    const int*   src  = (const int*)d_in[1];
    const int*   dst  = (const int*)d_in[2];
    const int*   gid  = (const int*)d_in[3];
    const float* W1   = (const float*)d_in[4];
    const float* b1   = (const float*)d_in[5];
    const float* W2   = (const float*)d_in[6];
    const float* b2   = (const float*)d_in[7];
    const float* Wd1  = (const float*)d_in[8];
    const float* bd1  = (const float*)d_in[9];
    const float* Wd2  = (const float*)d_in[10];
    const float* bd2  = (const float*)d_in[11];
    float* out = (float*)d_out;

    // workspace layout (4-byte-word offsets; 16B-aligned where vector-accessed)
    char* wsb = (char*)d_ws;
    int*   degi   = (int*)wsb;                                 // [100000]
    float* gcount = (float*)(wsb + 100000ll * 4);              // [64]
    float* hg_sum = (float*)(wsb + 100064ll * 4);              // [8192]
    int*   bsum   = (int*)(wsb + 108256ll * 4);                // [512]
    int*   boff   = (int*)(wsb + 108768ll * 4);                // [512]
    int*   off    = (int*)(wsb + 109280ll * 4);                // [100000]
    int*   bcur   = (int*)(wsb + 209280ll * 4);                // [6256] line-padded
    int*   eidx   = (int*)(wsb + 215536ll * 4);                // [3200000] padded CSR
    unsigned int* pbuf = (unsigned int*)(wsb + 3415536ll * 4); // [3200000]
    unsigned short* W1t = (unsigned short*)(wsb + 6615536ll * 4);  // bf16 [16384]
    unsigned short* W2t = (unsigned short*)(wsb + 6623728ll * 4);  // bf16 [16384]
    unsigned short* Yb  = (unsigned short*)(wsb + 6631920ll * 4);  // bf16 [(NN+1)*128]
    unsigned short* H1  = (unsigned short*)(wsb + 13032000ll * 4); // bf16 [NN*128]
    unsigned char*  Y8  = (unsigned char*)(wsb + 19432000ll * 4);  // fp8 [(NN+1)*128]

    // zero degi + gcount + hg_sum
    hipMemsetAsync(d_ws, 0, (size_t)108256 * 4, stream);

    // prep: degree hist + graph counts || Wt convert + dummy-row zeroes
    k_prep<<<6250 + 130, 256, 0, stream>>>(dst, gid, degi, gcount, W1, W2, W1t, W2t,
                                           Yb + (size_t)NN * FD,
                                           (unsigned int*)(Y8 + (size_t)NN * FD));
    // deterministic monotone off[] over padded degrees
    k_scan1<<<NBIN, 256, 0, stream>>>(degi, bsum);
    k_scan2<<<1, 512, 0, stream>>>(bsum, boff);
    k_scan3<<<NBIN, 256, 0, stream>>>(degi, boff, off, bcur, eidx);
    // pass 1: bin edges (contiguous bin regions)
    k_bin<<<(NE + 255) / 256, 256, 0, stream>>>(src, dst, bcur, pbuf);
    // pass 2 fill (bin-local scatter) || gemm1 (y1 = feat @ W1)
    k_work<<<NBIN * 5, 256, 0, stream>>>(pbuf, bcur, off, eidx, feat, W1t, Yb, Y8);
    // h1 = relu(y1_self + mean-agg(y1_fp8) + b1)
    k_agg<false><<<NN * 16 / 256, 256, 0, stream>>>(Yb, Y8, off, degi, eidx, b1, H1, nullptr, nullptr);
    // y2 = h1 @ W2
    k_gemm2<<<(NN + 63) / 64, 256, 0, stream>>>(H1, W2t, Yb, Y8);
    // h2 pooled per graph
    k_agg<true><<<NN * 16 / 256, 256, 0, stream>>>(Yb, Y8, off, degi, eidx, b2, nullptr, gid, hg_sum);
    // pool divide + decoder
    k_dec<<<NG, 128, 0, stream>>>(hg_sum, gcount, Wd1, bd1, Wd2, bd2, out);
}

// Round 13
// 362.283 us; speedup vs baseline: 1.0297x; 1.0201x over previous
//
#include <hip/hip_runtime.h>

#define NN 100000
#define NE 1600000
#define FD 128
#define NG 64
#define OUTD 64
#define NBIN 391   // ceil(NN/256); block==bin in scan/fill kernels

typedef __attribute__((ext_vector_type(8))) short bf16x8;
typedef __attribute__((ext_vector_type(4))) float f32x4;
typedef __attribute__((ext_vector_type(2))) float f32x2;
typedef __attribute__((ext_vector_type(8))) unsigned short u16x8;

static __device__ __forceinline__ void atomAddF(float* p, float v) {
    __hip_atomic_fetch_add(p, v, __ATOMIC_RELAXED, __HIP_MEMORY_SCOPE_AGENT);
}
static __device__ __forceinline__ int atomAddI(int* p, int v) {
    return __hip_atomic_fetch_add(p, v, __ATOMIC_RELAXED, __HIP_MEMORY_SCOPE_AGENT);
}
// fp32 -> bf16 round-to-nearest-even
static __device__ __forceinline__ unsigned short f2bf(float f) {
    unsigned int u = __float_as_uint(f);
    u += 0x7FFFu + ((u >> 16) & 1u);
    return (unsigned short)(u >> 16);
}
static __device__ __forceinline__ float bf2f(unsigned short h) {
    return __uint_as_float(((unsigned int)h) << 16);
}
// fp32 -> fp8 e4m3 (OCP on gfx950), HW convert
static __device__ __forceinline__ unsigned char f2fp8(float v) {
    return (unsigned char)(__builtin_amdgcn_cvt_pk_fp8_f32(v, v, 0, false) & 0xff);
}

// ===== k_prep: [0..6249] degree hist + graph counts; [6250..] Wt + dummy rows =====
__global__ __launch_bounds__(256) void k_prep(
    const int* __restrict__ dst, const int* __restrict__ gid,
    int* __restrict__ degi, float* __restrict__ gcount,
    const float* __restrict__ W1, const float* __restrict__ W2,
    unsigned short* __restrict__ W1t, unsigned short* __restrict__ W2t,
    unsigned short* __restrict__ Ydummy, unsigned int* __restrict__ Y8dummy,
    unsigned int* __restrict__ Y82dummy)
{
    if (blockIdx.x < 6250) {
        __shared__ float c[NG];
        if (threadIdx.x < NG) c[threadIdx.x] = 0.0f;
        __syncthreads();
        int i = blockIdx.x * 256 + threadIdx.x;
        if (i < NE) atomAddI(&degi[dst[i]], 1);
        if (i < NN) atomicAdd(&c[gid[i]], 1.0f);
        __syncthreads();
        if (threadIdx.x < NG) {
            float v = c[threadIdx.x];
            if (v != 0.0f) atomAddF(&gcount[threadIdx.x], v);
        }
    } else {
        int idx = (blockIdx.x - 6250) * 256 + threadIdx.x;
        if (idx < 32768) {
            const float* W = (idx < 16384) ? W1 : W2;
            unsigned short* Wt = (idx < 16384) ? W1t : W2t;
            int i = idx & 16383;
            int k = i >> 7, n = i & 127;
            Wt[n * 128 + k] = f2bf(W[i]);
        } else if (idx < 32768 + FD) {
            Ydummy[idx - 32768] = 0;             // zero bf16 Y row NN
        } else if (idx < 32768 + FD + 32) {
            Y8dummy[idx - 32768 - FD] = 0;       // zero fp8 Y row NN
        } else if (idx < 32768 + FD + 64) {
            Y82dummy[idx - 32768 - FD - 32] = 0; // zero fp8 Y2 row NN
        }
    }
}

// ===== deterministic scan over padded degrees, pad 8 (off[] MONOTONE) =====
__global__ void k_scan1(const int* __restrict__ degi, int* __restrict__ bsum) {
    __shared__ int s[256];
    int i = blockIdx.x * 256 + threadIdx.x;
    int d = (i < NN) ? degi[i] : 0;
    s[threadIdx.x] = (d + 7) & ~7;
    __syncthreads();
    for (int w = 128; w > 0; w >>= 1) {
        if (threadIdx.x < w) s[threadIdx.x] += s[threadIdx.x + w];
        __syncthreads();
    }
    if (threadIdx.x == 0) bsum[blockIdx.x] = s[0];
}

__global__ void k_scan2(const int* __restrict__ bsum, int* __restrict__ boff) {
    __shared__ int s[512];
    int t = threadIdx.x;
    int v = (t < NBIN) ? bsum[t] : 0;
    s[t] = v;
    __syncthreads();
    for (int d = 1; d < 512; d <<= 1) {
        int x = (t >= d) ? s[t - d] : 0;
        __syncthreads();
        s[t] += x;
        __syncthreads();
    }
    if (t < NBIN) boff[t] = s[t] - v;
}

__global__ void k_scan3(const int* __restrict__ degi, const int* __restrict__ boff,
                        int* __restrict__ off, int* __restrict__ bcur,
                        int* __restrict__ eidx) {
    __shared__ int s[256];
    int t = threadIdx.x;
    int i = blockIdx.x * 256 + t;
    int d = (i < NN) ? degi[i] : 0;
    int rd = (d + 7) & ~7;
    s[t] = rd;
    __syncthreads();
    for (int dd = 1; dd < 256; dd <<= 1) {
        int x = (t >= dd) ? s[t - dd] : 0;
        __syncthreads();
        s[t] += x;
        __syncthreads();
    }
    if (i < NN) {
        int o = boff[blockIdx.x] + s[t] - rd;
        off[i] = o;
        for (int j = d; j < rd; ++j) eidx[o + j] = NN;   // dummy idx
    }
    if (t == 0) bcur[blockIdx.x * 16] = boff[blockIdx.x];
}

// ===== pass 1: bin edges by dst>>8 into pbuf, packed (dstLocal<<17 | src) =====
__global__ void k_bin(const int* __restrict__ src, const int* __restrict__ dst,
                      int* __restrict__ bcur, unsigned int* __restrict__ pbuf) {
    int e = blockIdx.x * 256 + threadIdx.x;
    if (e < NE) {
        int d = dst[e];
        int b = d >> 8;
        int p = atomAddI(&bcur[b * 16], 1);
        pbuf[p] = ((unsigned int)(d & 255) << 17) | (unsigned int)src[e];
    }
}

// ===== no-LDS MFMA gemm body: Y (bf16+fp8) = A @ W, A fp32 from global =====
static __device__ __forceinline__ void gemm_body(
    int base, const float* __restrict__ feat, const unsigned short* __restrict__ Wt,
    unsigned short* __restrict__ Y, unsigned char* __restrict__ Y8)
{
    const int lane = threadIdx.x & 63;
    const int w = threadIdx.x >> 6;
    const int r = lane & 15;
    const int kb = lane >> 4;
    const int row = base + w * 16 + r;
    const bool rok = row < NN;

    bf16x8 a[4];
    #pragma unroll
    for (int kt = 0; kt < 4; ++kt) {
        float4 lo = {0,0,0,0}, hi = {0,0,0,0};
        if (rok) {
            const float4* p = reinterpret_cast<const float4*>(
                feat + (size_t)row * FD + kt * 32 + kb * 8);
            lo = p[0]; hi = p[1];
        }
        bf16x8 t;
        t[0] = (short)f2bf(lo.x); t[1] = (short)f2bf(lo.y);
        t[2] = (short)f2bf(lo.z); t[3] = (short)f2bf(lo.w);
        t[4] = (short)f2bf(hi.x); t[5] = (short)f2bf(hi.y);
        t[6] = (short)f2bf(hi.z); t[7] = (short)f2bf(hi.w);
        a[kt] = t;
    }

    f32x4 acc[8];
    #pragma unroll
    for (int ct = 0; ct < 8; ++ct) acc[ct] = (f32x4){0.f, 0.f, 0.f, 0.f};

    const int n = lane & 15;
    #pragma unroll
    for (int ct = 0; ct < 8; ++ct) {
        int col = ct * 16 + n;
        #pragma unroll
        for (int kt = 0; kt < 4; ++kt) {
            bf16x8 b = *reinterpret_cast<const bf16x8*>(
                Wt + (size_t)col * FD + kt * 32 + kb * 8);
            acc[ct] = __builtin_amdgcn_mfma_f32_16x16x32_bf16(a[kt], b, acc[ct], 0, 0, 0);
        }
    }

    const int rbase = base + w * 16 + (lane >> 4) * 4;
    #pragma unroll
    for (int reg = 0; reg < 4; ++reg) {
        int node = rbase + reg;
        if (node < NN) {
            #pragma unroll
            for (int ct = 0; ct < 8; ++ct) {
                float v = acc[ct][reg];
                Y[(size_t)node * FD + ct * 16 + n] = f2bf(v);
                Y8[(size_t)node * FD + ct * 16 + n] = f2fp8(v);
            }
        }
    }
}

// ===== k_work: [g%5==0] pass-2 fill (bin-local scatter); else gemm1 =====
__global__ __launch_bounds__(256) void k_work(
    const unsigned int* __restrict__ pbuf, const int* __restrict__ bcur,
    const int* __restrict__ off, int* __restrict__ eidx,
    const float* __restrict__ feat, const unsigned short* __restrict__ Wt,
    unsigned short* __restrict__ Y, unsigned char* __restrict__ Y8)
{
    int g = blockIdx.x;
    if (g % 5 != 0) {
        gemm_body((g - g / 5 - 1) * 64, feat, Wt, Y, Y8);
    } else {
        int b = g / 5;
        __shared__ int cur[256];
        const int t = threadIdx.x;
        const int v = (b << 8) + t;
        cur[t] = (v < NN) ? off[v] : 0;
        __syncthreads();
        const int st = off[b << 8];
        const int en = bcur[b * 16];
        for (int i = st + t; i < en; i += 256) {
            unsigned int pk = pbuf[i];
            int dl = (int)(pk >> 17);
            int s  = (int)(pk & 0x1FFFF);
            int p = atomicAdd(&cur[dl], 1);
            eidx[p] = s;
        }
    }
}

// ===== k_aggmm: agg layer-1 + fused M=16 MFMA gemm2 -> Y82 (fp8) =====
// Gather (chunk 8): h = relu(Yb[v] + mean Y8[u] + b1); A-tile to LDS bf16;
// 4 waves x 8 MFMAs with B from L1-hot W2t; y2 written fp8 to a NEW buffer
// (no race with concurrent y1 readers).
__global__ __launch_bounds__(256) void k_aggmm(
    const unsigned short* __restrict__ Y, const unsigned char* __restrict__ Y8,
    const int* __restrict__ off, const int* __restrict__ degi,
    const int* __restrict__ eidx, const float* __restrict__ bias,
    const unsigned short* __restrict__ Wt2, unsigned char* __restrict__ Y82)
{
    __shared__ unsigned short At[16 * FD];   // 4 KB, swizzled rows of 256B
    const int t = blockIdx.x * 256 + threadIdx.x;
    const int v = t >> 4;                 // node
    const int l = threadIdx.x & 15;       // 8-feature slice
    const int gb = threadIdx.x & 48;      // 16-lane group base within wave
    const int e0 = off[v];
    const int d  = degi[v];
    const int pd = (d + 7) & ~7;

    float a[8];
    #pragma unroll
    for (int j = 0; j < 8; ++j) a[j] = 0.0f;

    const uint2* Y8v = reinterpret_cast<const uint2*>(Y8);
    const int eend = e0 + pd;
    for (int e = e0; e < eend; e += 8) {
        int myidx = eidx[e + (l & 7)];
        #pragma unroll
        for (int j = 0; j < 8; ++j) {
            int s = __shfl(myidx, gb + j, 64);
            uint2 q = Y8v[(size_t)s * 16 + l];
            f32x2 v0 = __builtin_amdgcn_cvt_pk_f32_fp8((int)q.x, false);
            f32x2 v1 = __builtin_amdgcn_cvt_pk_f32_fp8((int)q.x, true);
            f32x2 v2 = __builtin_amdgcn_cvt_pk_f32_fp8((int)q.y, false);
            f32x2 v3 = __builtin_amdgcn_cvt_pk_f32_fp8((int)q.y, true);
            a[0] += v0[0]; a[1] += v0[1]; a[2] += v1[0]; a[3] += v1[1];
            a[4] += v2[0]; a[5] += v2[1]; a[6] += v3[0]; a[7] += v3[1];
        }
    }

    const float inv = 1.0f / fmaxf((float)d, 1.0f);
    const u16x8* Yv = reinterpret_cast<const u16x8*>(Y);
    u16x8 sv = Yv[(size_t)v * 16 + l];
    const float4* bp = reinterpret_cast<const float4*>(bias + l * 8);
    float4 b0 = bp[0], b1 = bp[1];
    const float* bb[8] = { &b0.x, &b0.y, &b0.z, &b0.w, &b1.x, &b1.y, &b1.z, &b1.w };

    // h (bf16) -> LDS A-tile, swizzled
    {
        u16x8 o;
        #pragma unroll
        for (int j = 0; j < 8; ++j)
            o[j] = f2bf(fmaxf(bf2f(sv[j]) + a[j] * inv + *bb[j], 0.0f));
        int g = threadIdx.x >> 4;   // local node 0..15
        char* AtB = reinterpret_cast<char*>(At);
        *reinterpret_cast<u16x8*>(AtB + g * 256 + ((l * 16) ^ ((g & 7) << 4))) = o;
    }
    __syncthreads();

    // M=16 GEMM: Y2[16 x 128] = At @ W2 ; wave w covers cols [32w, 32w+32)
    {
        const int lane = threadIdx.x & 63;
        const int w = threadIdx.x >> 6;
        const int r = lane & 15;
        const int kb = lane >> 4;
        const int n = lane & 15;
        char* AtB = reinterpret_cast<char*>(At);

        bf16x8 af[4];
        #pragma unroll
        for (int kt = 0; kt < 4; ++kt)
            af[kt] = *reinterpret_cast<bf16x8*>(
                AtB + r * 256 + ((kt * 64 + kb * 16) ^ ((r & 7) << 4)));

        f32x4 acc[2];
        acc[0] = (f32x4){0.f, 0.f, 0.f, 0.f};
        acc[1] = (f32x4){0.f, 0.f, 0.f, 0.f};
        #pragma unroll
        for (int ct = 0; ct < 2; ++ct) {
            int col = w * 32 + ct * 16 + n;
            #pragma unroll
            for (int kt = 0; kt < 4; ++kt) {
                bf16x8 bf = *reinterpret_cast<const bf16x8*>(
                    Wt2 + (size_t)col * FD + kt * 32 + kb * 8);
                acc[ct] = __builtin_amdgcn_mfma_f32_16x16x32_bf16(af[kt], bf, acc[ct], 0, 0, 0);
            }
        }

        const int nb = blockIdx.x * 16 + (lane >> 4) * 4;
        #pragma unroll
        for (int reg = 0; reg < 4; ++reg) {
            #pragma unroll
            for (int ct = 0; ct < 2; ++ct)
                Y82[(size_t)(nb + reg) * FD + w * 32 + ct * 16 + n] = f2fp8(acc[ct][reg]);
        }
    }
}

// ===== k_aggp: agg layer-2 (all-fp8 reads) + per-graph pooling =====
__global__ __launch_bounds__(256) void k_aggp(
    const unsigned char* __restrict__ Y82, const int* __restrict__ off,
    const int* __restrict__ degi, const int* __restrict__ eidx,
    const float* __restrict__ bias,
    const int* __restrict__ gid, float* __restrict__ hg_sum)
{
    __shared__ float hl[FD];
    if (threadIdx.x < FD) hl[threadIdx.x] = 0.0f;
    int gid0 = gid[blockIdx.x * 16];
    __syncthreads();

    const int t = blockIdx.x * 256 + threadIdx.x;
    const int v = t >> 4;
    const int l = threadIdx.x & 15;
    const int gb = threadIdx.x & 48;
    const int e0 = off[v];
    const int d  = degi[v];
    const int pd = (d + 7) & ~7;

    float a[8];
    #pragma unroll
    for (int j = 0; j < 8; ++j) a[j] = 0.0f;

    const uint2* Y8v = reinterpret_cast<const uint2*>(Y82);
    const int eend = e0 + pd;
    for (int e = e0; e < eend; e += 8) {
        int myidx = eidx[e + (l & 7)];
        #pragma unroll
        for (int j = 0; j < 8; ++j) {
            int s = __shfl(myidx, gb + j, 64);
            uint2 q = Y8v[(size_t)s * 16 + l];
            f32x2 v0 = __builtin_amdgcn_cvt_pk_f32_fp8((int)q.x, false);
            f32x2 v1 = __builtin_amdgcn_cvt_pk_f32_fp8((int)q.x, true);
            f32x2 v2 = __builtin_amdgcn_cvt_pk_f32_fp8((int)q.y, false);
            f32x2 v3 = __builtin_amdgcn_cvt_pk_f32_fp8((int)q.y, true);
            a[0] += v0[0]; a[1] += v0[1]; a[2] += v1[0]; a[3] += v1[1];
            a[4] += v2[0]; a[5] += v2[1]; a[6] += v3[0]; a[7] += v3[1];
        }
    }

    const float inv = 1.0f / fmaxf((float)d, 1.0f);
    uint2 qs = Y8v[(size_t)v * 16 + l];      // self term (fp8 y2)
    f32x2 s0 = __builtin_amdgcn_cvt_pk_f32_fp8((int)qs.x, false);
    f32x2 s1 = __builtin_amdgcn_cvt_pk_f32_fp8((int)qs.x, true);
    f32x2 s2 = __builtin_amdgcn_cvt_pk_f32_fp8((int)qs.y, false);
    f32x2 s3 = __builtin_amdgcn_cvt_pk_f32_fp8((int)qs.y, true);
    float sf[8] = { s0[0], s0[1], s1[0], s1[1], s2[0], s2[1], s3[0], s3[1] };
    const float4* bp = reinterpret_cast<const float4*>(bias + l * 8);
    float4 b0 = bp[0], b1 = bp[1];
    const float* bb[8] = { &b0.x, &b0.y, &b0.z, &b0.w, &b1.x, &b1.y, &b1.z, &b1.w };

    float hv[8];
    #pragma unroll
    for (int j = 0; j < 8; ++j)
        hv[j] = fmaxf(sf[j] + a[j] * inv + *bb[j], 0.0f);

    int g = gid[v];
    int fo = l * 8;
    if (g == gid0) {
        #pragma unroll
        for (int j = 0; j < 8; ++j) atomicAdd(&hl[fo + j], hv[j]);
    } else {
        #pragma unroll
        for (int j = 0; j < 8; ++j) atomAddF(&hg_sum[(size_t)g * FD + fo + j], hv[j]);
    }
    __syncthreads();
    if (threadIdx.x < FD)
        atomAddF(&hg_sum[(size_t)gid0 * FD + threadIdx.x], hl[threadIdx.x]);
}

// ===== fused decoder: one block per graph =====
__global__ __launch_bounds__(128) void k_dec(
    const float* __restrict__ hg_sum, const float* __restrict__ gcount,
    const float* __restrict__ Wd1, const float* __restrict__ bd1,
    const float* __restrict__ Wd2, const float* __restrict__ bd2,
    float* __restrict__ out)
{
    __shared__ float hgL[FD];
    __shared__ float t1L[FD];
    const int g = blockIdx.x;
    const int t = threadIdx.x;
    const float invc = 1.0f / fmaxf(gcount[g], 1.0f);

    float v = hg_sum[(size_t)g * FD + t] * invc;
    hgL[t] = v;
    out[(size_t)g * FD + t] = v;
    __syncthreads();

    float acc = bd1[t];
    #pragma unroll 8
    for (int k = 0; k < FD; ++k)
        acc += hgL[k] * Wd1[k * FD + t];
    t1L[t] = fmaxf(acc, 0.0f);
    __syncthreads();

    if (t < OUTD) {
        float acc2 = bd2[t];
        #pragma unroll 8
        for (int k = 0; k < FD; ++k)
            acc2 += t1L[k] * Wd2[k * OUTD + t];
        out[NG * FD + (size_t)g * OUTD + t] = acc2;
    }
}

extern "C" void kernel_launch(void* const* d_in, const int* in_sizes, int n_in,
                              void* d_out, int out_size, void* d_ws, size_t ws_size,
                              hipStream_t stream) {
    const float* feat = (const float*)d_in[0];
    const int*   src  = (const int*)d_in[1];
    const int*   dst  = (const int*)d_in[2];
    const int*   gid  = (const int*)d_in[3];
    const float* W1   = (const float*)d_in[4];
    const float* b1   = (const float*)d_in[5];
    const float* W2   = (const float*)d_in[6];
    const float* b2   = (const float*)d_in[7];
    const float* Wd1  = (const float*)d_in[8];
    const float* bd1  = (const float*)d_in[9];
    const float* Wd2  = (const float*)d_in[10];
    const float* bd2  = (const float*)d_in[11];
    float* out = (float*)d_out;

    // workspace layout (4-byte-word offsets)
    char* wsb = (char*)d_ws;
    int*   degi   = (int*)wsb;                                 // [100000]
    float* gcount = (float*)(wsb + 100000ll * 4);              // [64]
    float* hg_sum = (float*)(wsb + 100064ll * 4);              // [8192]
    int*   bsum   = (int*)(wsb + 108256ll * 4);                // [512]
    int*   boff   = (int*)(wsb + 108768ll * 4);                // [512]
    int*   off    = (int*)(wsb + 109280ll * 4);                // [100000]
    int*   bcur   = (int*)(wsb + 209280ll * 4);                // [6256] line-padded
    int*   eidx   = (int*)(wsb + 215536ll * 4);                // [2400000] padded CSR (pad 8)
    unsigned int* pbuf = (unsigned int*)(wsb + 2615536ll * 4); // [2400000]
    unsigned short* W1t = (unsigned short*)(wsb + 5015536ll * 4);  // bf16 [16384]
    unsigned short* W2t = (unsigned short*)(wsb + 5023728ll * 4);  // bf16 [16384]
    unsigned short* Yb  = (unsigned short*)(wsb + 5031920ll * 4);  // bf16 [(NN+1)*128]
    unsigned char*  Y8  = (unsigned char*)(wsb + 11432000ll * 4);  // fp8 [(NN+1)*128] (y1)
    unsigned char*  Y82 = (unsigned char*)(wsb + 14632032ll * 4);  // fp8 [(NN+1)*128] (y2)

    // zero degi + gcount + hg_sum
    hipMemsetAsync(d_ws, 0, (size_t)108256 * 4, stream);

    // prep: degree hist + graph counts || Wt convert + dummy-row zeroes
    k_prep<<<6250 + 129, 256, 0, stream>>>(dst, gid, degi, gcount, W1, W2, W1t, W2t,
                                           Yb + (size_t)NN * FD,
                                           (unsigned int*)(Y8 + (size_t)NN * FD),
                                           (unsigned int*)(Y82 + (size_t)NN * FD));
    // deterministic monotone off[] over padded degrees (pad 8)
    k_scan1<<<NBIN, 256, 0, stream>>>(degi, bsum);
    k_scan2<<<1, 512, 0, stream>>>(bsum, boff);
    k_scan3<<<NBIN, 256, 0, stream>>>(degi, boff, off, bcur, eidx);
    // pass 1: bin edges
    k_bin<<<(NE + 255) / 256, 256, 0, stream>>>(src, dst, bcur, pbuf);
    // pass 2 fill (bin-local scatter) || gemm1 (y1 = feat @ W1 -> Yb + Y8)
    k_work<<<NBIN * 5, 256, 0, stream>>>(pbuf, bcur, off, eidx, feat, W1t, Yb, Y8);
    // agg1 + fused gemm2: h1 = relu(y1s + mean(y1) + b1); y2 = h1 @ W2 -> Y82
    k_aggmm<<<NN / 16, 256, 0, stream>>>(Yb, Y8, off, degi, eidx, b1, W2t, Y82);
    // agg2 + per-graph pooling (all-fp8)
    k_aggp<<<NN / 16, 256, 0, stream>>>(Y82, off, degi, eidx, b2, gid, hg_sum);
    // pool divide + decoder
    k_dec<<<NG, 128, 0, stream>>>(hg_sum, gcount, Wd1, bd1, Wd2, bd2, out);
}

// Round 14
// 294.490 us; speedup vs baseline: 1.2668x; 1.2302x over previous
//
#include <hip/hip_runtime.h>

#define NN 100000
#define NE 1600000
#define FD 128
#define NG 64
#define OUTD 64
#define NBIN 391   // ceil(NN/256)

typedef __attribute__((ext_vector_type(8))) short bf16x8;
typedef __attribute__((ext_vector_type(4))) float f32x4;
typedef __attribute__((ext_vector_type(2))) float f32x2;
typedef __attribute__((ext_vector_type(8))) unsigned short u16x8;

static __device__ __forceinline__ void atomAddF(float* p, float v) {
    __hip_atomic_fetch_add(p, v, __ATOMIC_RELAXED, __HIP_MEMORY_SCOPE_AGENT);
}
static __device__ __forceinline__ int atomAddI(int* p, int v) {
    return __hip_atomic_fetch_add(p, v, __ATOMIC_RELAXED, __HIP_MEMORY_SCOPE_AGENT);
}
static __device__ __forceinline__ unsigned short f2bf(float f) {
    unsigned int u = __float_as_uint(f);
    u += 0x7FFFu + ((u >> 16) & 1u);
    return (unsigned short)(u >> 16);
}
static __device__ __forceinline__ float bf2f(unsigned short h) {
    return __uint_as_float(((unsigned int)h) << 16);
}
static __device__ __forceinline__ unsigned char f2fp8(float v) {
    return (unsigned char)(__builtin_amdgcn_cvt_pk_fp8_f32(v, v, 0, false) & 0xff);
}

// ===== K1 k_pre: [0..390] per-BIN edge hist; [391..781] graph counts;
//                 [782..910] Wt convert + fp8 dummy rows =====
__global__ __launch_bounds__(256) void k_pre(
    const int* __restrict__ dst, const int* __restrict__ gid,
    int* __restrict__ bincnt, float* __restrict__ gcount,
    const float* __restrict__ W1, const float* __restrict__ W2,
    unsigned short* __restrict__ W1t, unsigned short* __restrict__ W2t,
    unsigned int* __restrict__ Y8dummy, unsigned int* __restrict__ Y82dummy)
{
    const int t = threadIdx.x;
    if (blockIdx.x < NBIN) {
        __shared__ int h[NBIN];
        for (int i = t; i < NBIN; i += 256) h[i] = 0;
        __syncthreads();
        int e0 = blockIdx.x * 4096;
        int e1 = min(e0 + 4096, NE);
        for (int e = e0 + t; e < e1; e += 256)
            atomicAdd(&h[dst[e] >> 8], 1);
        __syncthreads();
        for (int i = t; i < NBIN; i += 256)
            if (h[i]) atomAddI(&bincnt[i], h[i]);
    } else if (blockIdx.x < 2 * NBIN) {
        __shared__ float c[NG];
        if (t < NG) c[t] = 0.0f;
        __syncthreads();
        int i = (blockIdx.x - NBIN) * 256 + t;
        if (i < NN) atomicAdd(&c[gid[i]], 1.0f);
        __syncthreads();
        if (t < NG) {
            float v = c[t];
            if (v != 0.0f) atomAddF(&gcount[t], v);
        }
    } else {
        int idx = (blockIdx.x - 2 * NBIN) * 256 + t;
        if (idx < 32768) {
            const float* W = (idx < 16384) ? W1 : W2;
            unsigned short* Wt = (idx < 16384) ? W1t : W2t;
            int i = idx & 16383;
            int k = i >> 7, n = i & 127;
            Wt[n * 128 + k] = f2bf(W[i]);
        } else if (idx < 32768 + 32) {
            Y8dummy[idx - 32768] = 0;
        } else if (idx < 32768 + 64) {
            Y82dummy[idx - 32768 - 32] = 0;
        }
    }
}

// ===== K2: scan 391 bin counts -> pstart (pbuf) ; bcur init =====
// eidx region for bin b starts at pstart[b] + b*2048 (constant pad capacity).
__global__ void k_boff(const int* __restrict__ bincnt, int* __restrict__ pstart,
                       int* __restrict__ bcur) {
    __shared__ int s[512];
    int t = threadIdx.x;
    int v = (t < NBIN) ? bincnt[t] : 0;
    s[t] = v;
    __syncthreads();
    for (int d = 1; d < 512; d <<= 1) {
        int x = (t >= d) ? s[t - d] : 0;
        __syncthreads();
        s[t] += x;
        __syncthreads();
    }
    if (t < NBIN) {
        int p = s[t] - v;
        pstart[t] = p;
        bcur[t * 16] = p;
    }
}

// ===== no-LDS MFMA gemm1 body: Y8 (fp8) = feat @ W1 =====
static __device__ __forceinline__ void gemm_body(
    int base, const float* __restrict__ feat, const unsigned short* __restrict__ Wt,
    unsigned char* __restrict__ Y8)
{
    const int lane = threadIdx.x & 63;
    const int w = threadIdx.x >> 6;
    const int r = lane & 15;
    const int kb = lane >> 4;
    const int row = base + w * 16 + r;
    const bool rok = row < NN;

    bf16x8 a[4];
    #pragma unroll
    for (int kt = 0; kt < 4; ++kt) {
        float4 lo = {0,0,0,0}, hi = {0,0,0,0};
        if (rok) {
            const float4* p = reinterpret_cast<const float4*>(
                feat + (size_t)row * FD + kt * 32 + kb * 8);
            lo = p[0]; hi = p[1];
        }
        bf16x8 t;
        t[0] = (short)f2bf(lo.x); t[1] = (short)f2bf(lo.y);
        t[2] = (short)f2bf(lo.z); t[3] = (short)f2bf(lo.w);
        t[4] = (short)f2bf(hi.x); t[5] = (short)f2bf(hi.y);
        t[6] = (short)f2bf(hi.z); t[7] = (short)f2bf(hi.w);
        a[kt] = t;
    }

    f32x4 acc[8];
    #pragma unroll
    for (int ct = 0; ct < 8; ++ct) acc[ct] = (f32x4){0.f, 0.f, 0.f, 0.f};

    const int n = lane & 15;
    #pragma unroll
    for (int ct = 0; ct < 8; ++ct) {
        int col = ct * 16 + n;
        #pragma unroll
        for (int kt = 0; kt < 4; ++kt) {
            bf16x8 b = *reinterpret_cast<const bf16x8*>(
                Wt + (size_t)col * FD + kt * 32 + kb * 8);
            acc[ct] = __builtin_amdgcn_mfma_f32_16x16x32_bf16(a[kt], b, acc[ct], 0, 0, 0);
        }
    }

    const int rbase = base + w * 16 + (lane >> 4) * 4;
    #pragma unroll
    for (int reg = 0; reg < 4; ++reg) {
        int node = rbase + reg;
        if (node < NN) {
            #pragma unroll
            for (int ct = 0; ct < 8; ++ct)
                Y8[(size_t)node * FD + ct * 16 + n] = f2fp8(acc[ct][reg]);
        }
    }
}

// ===== K3 k_mix: [g%5==0] gemm1; else bin-append pass =====
__global__ __launch_bounds__(256) void k_mix(
    const int* __restrict__ src, const int* __restrict__ dst,
    int* __restrict__ bcur, unsigned int* __restrict__ pbuf,
    const float* __restrict__ feat, const unsigned short* __restrict__ Wt,
    unsigned char* __restrict__ Y8)
{
    int g = blockIdx.x;
    if (g % 5 == 0) {
        gemm_body((g / 5) * 64, feat, Wt, Y8);
    } else {
        int fb = g - g / 5 - 1;
        int e = fb * 256 + threadIdx.x;
        if (e < NE) {
            int d = dst[e];
            int b = d >> 8;
            int p = atomAddI(&bcur[b * 16], 1);
            pbuf[p] = ((unsigned int)(d & 255) << 17) | (unsigned int)src[e];
        }
    }
}

// ===== K4 k_fill2: bin-local CSR build (degrees, offsets, padding, scatter) =====
__global__ __launch_bounds__(256) void k_fill2(
    const unsigned int* __restrict__ pbuf, const int* __restrict__ pstart,
    const int* __restrict__ bcur, int* __restrict__ degi, int* __restrict__ off,
    int* __restrict__ eidx)
{
    __shared__ int ldeg[256], lpre[256], lcur[256];
    const int b = blockIdx.x;
    const int t = threadIdx.x;
    const int st = pstart[b];
    const int en = bcur[b * 16];
    const int cnt = en - st;

    ldeg[t] = 0;
    __syncthreads();
    for (int i = t; i < cnt; i += 256)
        atomicAdd(&ldeg[(int)(pbuf[st + i] >> 17)], 1);
    __syncthreads();

    const int d = ldeg[t];
    const int rd = (d + 7) & ~7;
    lpre[t] = rd;
    __syncthreads();
    for (int dd = 1; dd < 256; dd <<= 1) {
        int x = (t >= dd) ? lpre[t - dd] : 0;
        __syncthreads();
        lpre[t] += x;
        __syncthreads();
    }

    const int ebase = st + b * 2048;            // eidx region start for bin b
    const int o = ebase + lpre[t] - rd;
    const int v = (b << 8) + t;
    if (v < NN) {
        degi[v] = d;
        off[v] = o;
        for (int j = d; j < rd; ++j) eidx[o + j] = NN;   // dummy padding
    }
    lcur[t] = o;
    __syncthreads();

    for (int i = t; i < cnt; i += 256) {
        unsigned int pk = pbuf[st + i];
        int dl = (int)(pk >> 17);
        int s  = (int)(pk & 0x1FFFF);
        int p = atomicAdd(&lcur[dl], 1);
        eidx[p] = s;
    }
}

// ===== K5 k_aggmm: agg layer-1 (all fp8) + fused M=16 MFMA gemm2 -> Y82 =====
__global__ __launch_bounds__(256) void k_aggmm(
    const unsigned char* __restrict__ Y8, const int* __restrict__ off,
    const int* __restrict__ degi, const int* __restrict__ eidx,
    const float* __restrict__ bias, const unsigned short* __restrict__ Wt2,
    unsigned char* __restrict__ Y82)
{
    __shared__ unsigned short At[16 * FD];   // 4 KB, swizzled rows of 256B
    const int t = blockIdx.x * 256 + threadIdx.x;
    const int v = t >> 4;
    const int l = threadIdx.x & 15;
    const int gb = threadIdx.x & 48;
    const int e0 = off[v];
    const int d  = degi[v];
    const int pd = (d + 7) & ~7;

    float a[8];
    #pragma unroll
    for (int j = 0; j < 8; ++j) a[j] = 0.0f;

    const uint2* Y8v = reinterpret_cast<const uint2*>(Y8);
    const int eend = e0 + pd;
    for (int e = e0; e < eend; e += 8) {
        int myidx = eidx[e + (l & 7)];
        #pragma unroll
        for (int j = 0; j < 8; ++j) {
            int s = __shfl(myidx, gb + j, 64);
            uint2 q = Y8v[(size_t)s * 16 + l];
            f32x2 v0 = __builtin_amdgcn_cvt_pk_f32_fp8((int)q.x, false);
            f32x2 v1 = __builtin_amdgcn_cvt_pk_f32_fp8((int)q.x, true);
            f32x2 v2 = __builtin_amdgcn_cvt_pk_f32_fp8((int)q.y, false);
            f32x2 v3 = __builtin_amdgcn_cvt_pk_f32_fp8((int)q.y, true);
            a[0] += v0[0]; a[1] += v0[1]; a[2] += v1[0]; a[3] += v1[1];
            a[4] += v2[0]; a[5] += v2[1]; a[6] += v3[0]; a[7] += v3[1];
        }
    }

    const float inv = 1.0f / fmaxf((float)d, 1.0f);
    uint2 qs = Y8v[(size_t)v * 16 + l];          // fp8 self term
    f32x2 s0 = __builtin_amdgcn_cvt_pk_f32_fp8((int)qs.x, false);
    f32x2 s1 = __builtin_amdgcn_cvt_pk_f32_fp8((int)qs.x, true);
    f32x2 s2 = __builtin_amdgcn_cvt_pk_f32_fp8((int)qs.y, false);
    f32x2 s3 = __builtin_amdgcn_cvt_pk_f32_fp8((int)qs.y, true);
    float sf[8] = { s0[0], s0[1], s1[0], s1[1], s2[0], s2[1], s3[0], s3[1] };
    const float4* bp = reinterpret_cast<const float4*>(bias + l * 8);
    float4 b0 = bp[0], b1 = bp[1];
    const float* bb[8] = { &b0.x, &b0.y, &b0.z, &b0.w, &b1.x, &b1.y, &b1.z, &b1.w };

    // h1 (bf16) -> LDS A-tile, swizzled
    {
        u16x8 o;
        #pragma unroll
        for (int j = 0; j < 8; ++j)
            o[j] = f2bf(fmaxf(sf[j] + a[j] * inv + *bb[j], 0.0f));
        int g = threadIdx.x >> 4;
        char* AtB = reinterpret_cast<char*>(At);
        *reinterpret_cast<u16x8*>(AtB + g * 256 + ((l * 16) ^ ((g & 7) << 4))) = o;
    }
    __syncthreads();

    // M=16 GEMM: Y2[16x128] = At @ W2 ; wave w covers cols [32w, 32w+32)
    {
        const int lane = threadIdx.x & 63;
        const int w = threadIdx.x >> 6;
        const int r = lane & 15;
        const int kb = lane >> 4;
        const int n = lane & 15;
        char* AtB = reinterpret_cast<char*>(At);

        bf16x8 af[4];
        #pragma unroll
        for (int kt = 0; kt < 4; ++kt)
            af[kt] = *reinterpret_cast<bf16x8*>(
                AtB + r * 256 + ((kt * 64 + kb * 16) ^ ((r & 7) << 4)));

        f32x4 acc[2];
        acc[0] = (f32x4){0.f, 0.f, 0.f, 0.f};
        acc[1] = (f32x4){0.f, 0.f, 0.f, 0.f};
        #pragma unroll
        for (int ct = 0; ct < 2; ++ct) {
            int col = w * 32 + ct * 16 + n;
            #pragma unroll
            for (int kt = 0; kt < 4; ++kt) {
                bf16x8 bf = *reinterpret_cast<const bf16x8*>(
                    Wt2 + (size_t)col * FD + kt * 32 + kb * 8);
                acc[ct] = __builtin_amdgcn_mfma_f32_16x16x32_bf16(af[kt], bf, acc[ct], 0, 0, 0);
            }
        }

        const int nb = blockIdx.x * 16 + (lane >> 4) * 4;
        #pragma unroll
        for (int reg = 0; reg < 4; ++reg) {
            #pragma unroll
            for (int ct = 0; ct < 2; ++ct)
                Y82[(size_t)(nb + reg) * FD + w * 32 + ct * 16 + n] = f2fp8(acc[ct][reg]);
        }
    }
}

// ===== K6 k_aggp: agg layer-2 (all-fp8) + per-graph pooling =====
__global__ __launch_bounds__(256) void k_aggp(
    const unsigned char* __restrict__ Y82, const int* __restrict__ off,
    const int* __restrict__ degi, const int* __restrict__ eidx,
    const float* __restrict__ bias,
    const int* __restrict__ gid, float* __restrict__ hg_sum)
{
    __shared__ float hl[FD];
    if (threadIdx.x < FD) hl[threadIdx.x] = 0.0f;
    int gid0 = gid[blockIdx.x * 16];
    __syncthreads();

    const int t = blockIdx.x * 256 + threadIdx.x;
    const int v = t >> 4;
    const int l = threadIdx.x & 15;
    const int gb = threadIdx.x & 48;
    const int e0 = off[v];
    const int d  = degi[v];
    const int pd = (d + 7) & ~7;

    float a[8];
    #pragma unroll
    for (int j = 0; j < 8; ++j) a[j] = 0.0f;

    const uint2* Y8v = reinterpret_cast<const uint2*>(Y82);
    const int eend = e0 + pd;
    for (int e = e0; e < eend; e += 8) {
        int myidx = eidx[e + (l & 7)];
        #pragma unroll
        for (int j = 0; j < 8; ++j) {
            int s = __shfl(myidx, gb + j, 64);
            uint2 q = Y8v[(size_t)s * 16 + l];
            f32x2 v0 = __builtin_amdgcn_cvt_pk_f32_fp8((int)q.x, false);
            f32x2 v1 = __builtin_amdgcn_cvt_pk_f32_fp8((int)q.x, true);
            f32x2 v2 = __builtin_amdgcn_cvt_pk_f32_fp8((int)q.y, false);
            f32x2 v3 = __builtin_amdgcn_cvt_pk_f32_fp8((int)q.y, true);
            a[0] += v0[0]; a[1] += v0[1]; a[2] += v1[0]; a[3] += v1[1];
            a[4] += v2[0]; a[5] += v2[1]; a[6] += v3[0]; a[7] += v3[1];
        }
    }

    const float inv = 1.0f / fmaxf((float)d, 1.0f);
    uint2 qs = Y8v[(size_t)v * 16 + l];
    f32x2 s0 = __builtin_amdgcn_cvt_pk_f32_fp8((int)qs.x, false);
    f32x2 s1 = __builtin_amdgcn_cvt_pk_f32_fp8((int)qs.x, true);
    f32x2 s2 = __builtin_amdgcn_cvt_pk_f32_fp8((int)qs.y, false);
    f32x2 s3 = __builtin_amdgcn_cvt_pk_f32_fp8((int)qs.y, true);
    float sf[8] = { s0[0], s0[1], s1[0], s1[1], s2[0], s2[1], s3[0], s3[1] };
    const float4* bp = reinterpret_cast<const float4*>(bias + l * 8);
    float4 b0 = bp[0], b1 = bp[1];
    const float* bb[8] = { &b0.x, &b0.y, &b0.z, &b0.w, &b1.x, &b1.y, &b1.z, &b1.w };

    float hv[8];
    #pragma unroll
    for (int j = 0; j < 8; ++j)
        hv[j] = fmaxf(sf[j] + a[j] * inv + *bb[j], 0.0f);

    int g = gid[v];
    int fo = l * 8;
    if (g == gid0) {
        #pragma unroll
        for (int j = 0; j < 8; ++j) atomicAdd(&hl[fo + j], hv[j]);
    } else {
        #pragma unroll
        for (int j = 0; j < 8; ++j) atomAddF(&hg_sum[(size_t)g * FD + fo + j], hv[j]);
    }
    __syncthreads();
    if (threadIdx.x < FD)
        atomAddF(&hg_sum[(size_t)gid0 * FD + threadIdx.x], hl[threadIdx.x]);
}

// ===== K7 fused decoder: one block per graph =====
__global__ __launch_bounds__(128) void k_dec(
    const float* __restrict__ hg_sum, const float* __restrict__ gcount,
    const float* __restrict__ Wd1, const float* __restrict__ bd1,
    const float* __restrict__ Wd2, const float* __restrict__ bd2,
    float* __restrict__ out)
{
    __shared__ float hgL[FD];
    __shared__ float t1L[FD];
    const int g = blockIdx.x;
    const int t = threadIdx.x;
    const float invc = 1.0f / fmaxf(gcount[g], 1.0f);

    float v = hg_sum[(size_t)g * FD + t] * invc;
    hgL[t] = v;
    out[(size_t)g * FD + t] = v;
    __syncthreads();

    float acc = bd1[t];
    #pragma unroll 8
    for (int k = 0; k < FD; ++k)
        acc += hgL[k] * Wd1[k * FD + t];
    t1L[t] = fmaxf(acc, 0.0f);
    __syncthreads();

    if (t < OUTD) {
        float acc2 = bd2[t];
        #pragma unroll 8
        for (int k = 0; k < FD; ++k)
            acc2 += t1L[k] * Wd2[k * OUTD + t];
        out[NG * FD + (size_t)g * OUTD + t] = acc2;
    }
}

extern "C" void kernel_launch(void* const* d_in, const int* in_sizes, int n_in,
                              void* d_out, int out_size, void* d_ws, size_t ws_size,
                              hipStream_t stream) {
    const float* feat = (const float*)d_in[0];
    const int*   src  = (const int*)d_in[1];
    const int*   dst  = (const int*)d_in[2];
    const int*   gid  = (const int*)d_in[3];
    const float* W1   = (const float*)d_in[4];
    const float* b1   = (const float*)d_in[5];
    const float* W2   = (const float*)d_in[6];
    const float* b2   = (const float*)d_in[7];
    const float* Wd1  = (const float*)d_in[8];
    const float* bd1  = (const float*)d_in[9];
    const float* Wd2  = (const float*)d_in[10];
    const float* bd2  = (const float*)d_in[11];
    float* out = (float*)d_out;

    // workspace layout (4-byte-word offsets)
    char* wsb = (char*)d_ws;
    int*   bincnt = (int*)wsb;                                 // [512]
    float* gcount = (float*)(wsb + 512ll * 4);                 // [64]
    float* hg_sum = (float*)(wsb + 576ll * 4);                 // [8192]
    int*   pstart = (int*)(wsb + 8768ll * 4);                  // [512]
    int*   bcur   = (int*)(wsb + 9280ll * 4);                  // [6256] line-padded
    int*   degi   = (int*)(wsb + 15536ll * 4);                 // [100000]
    int*   off    = (int*)(wsb + 115536ll * 4);                // [100000]
    int*   eidx   = (int*)(wsb + 215536ll * 4);                // [2400800] padded CSR
    unsigned int* pbuf = (unsigned int*)(wsb + 2616336ll * 4); // [1600000]
    unsigned short* W1t = (unsigned short*)(wsb + 4216336ll * 4);  // bf16 [16384]
    unsigned short* W2t = (unsigned short*)(wsb + 4224528ll * 4);  // bf16 [16384]
    unsigned char*  Y8  = (unsigned char*)(wsb + 4232720ll * 4);   // fp8 [(NN+1)*128]
    unsigned char*  Y82 = (unsigned char*)(wsb + 7432752ll * 4);   // fp8 [(NN+1)*128]

    // zero bincnt + gcount + hg_sum
    hipMemsetAsync(d_ws, 0, (size_t)8768 * 4, stream);

    // K1: bin hist || graph counts || Wt + dummy rows
    k_pre<<<2 * NBIN + 129, 256, 0, stream>>>(dst, gid, bincnt, gcount, W1, W2,
                                              W1t, W2t,
                                              (unsigned int*)(Y8 + (size_t)NN * FD),
                                              (unsigned int*)(Y82 + (size_t)NN * FD));
    // K2: bin scan
    k_boff<<<1, 512, 0, stream>>>(bincnt, pstart, bcur);
    // K3: bin append || gemm1 (y1 = feat @ W1 -> Y8 fp8)
    k_mix<<<7815, 256, 0, stream>>>(src, dst, bcur, pbuf, feat, W1t, Y8);
    // K4: bin-local CSR build
    k_fill2<<<NBIN, 256, 0, stream>>>(pbuf, pstart, bcur, degi, off, eidx);
    // K5: agg1 + fused gemm2 -> Y82
    k_aggmm<<<NN / 16, 256, 0, stream>>>(Y8, off, degi, eidx, b1, W2t, Y82);
    // K6: agg2 + per-graph pooling
    k_aggp<<<NN / 16, 256, 0, stream>>>(Y82, off, degi, eidx, b2, gid, hg_sum);
    // K7: pool divide + decoder
    k_dec<<<NG, 128, 0, stream>>>(hg_sum, gcount, Wd1, bd1, Wd2, bd2, out);
}